// Round 1
// baseline (1383.198 us; speedup 1.0000x reference)
//
#include <hip/hip_runtime.h>
#include <stdint.h>

// Two-phase LoadingModel CAVI update: n=1000, p=50000, z=20, l=10.
//
// Phase A (392x128, all CUs, plain launch): bandwidth phase.
//   ztx[k][col] = sum_n mean_z[n,k]*data[n,col];  W[j][col] = sum_l mw*alpha;
//   var_w. ztx/W are stashed in the OUT buffers (ztx -> out_mw[0..20*50176),
//   W -> out_alpha[0..20*50176)). Safe: phase B reads the stash before its
//   first global sync; the only pre-sync store overlapping the stash region
//   is step (0,0)'s out_mw[gid], which is a same-thread read-then-write.
//
// Phase B (cooperative 49x1024): latency phase — 200 sequential global
//   softmaxes. Fewer, larger blocks shrink the all-reduce: 49 slots means a
//   SINGLE poll load per lane (vs 4), 7 cache lines of slots (vs 25), 16x
//   less poll traffic contending with the publishes. Flat one-hop retained:
//   every block publishes one tagged u64 (block lse), wave 0 of every block
//   polls all 49 slots, merges via shuffles, broadcasts through LDS.

#define NTA 128
#define NBLKA 392
#define NT_B 1024
#define NBLK_B 49
#define NWAVE_B (NT_B / 64)
#define PSTRIDE 50176

constexpr int N_DIM = 1000;
constexpr int P_DIM = 50000;
constexpr int Z_DIM = 20;
constexpr int L_DIM = 10;

static_assert(NTA * NBLKA == PSTRIDE, "phase A covers PSTRIDE columns");
static_assert(NT_B * NBLK_B == PSTRIDE, "phase B covers PSTRIDE columns");

using u64 = unsigned long long;

__device__ __forceinline__ float wred_max(float v) {
#pragma unroll
  for (int m = 32; m; m >>= 1) v = fmaxf(v, __shfl_xor(v, m, 64));
  return v;
}
__device__ __forceinline__ float wred_sum(float v) {
#pragma unroll
  for (int m = 32; m; m >>= 1) v += __shfl_xor(v, m, 64);
  return v;
}

// ---------------- Phase A: bandwidth-bound precompute ----------------
__global__ __launch_bounds__(NTA) void precompute_kernel(
    const float* __restrict__ data,      // [n, p]
    const float* __restrict__ mean_z,    // [n, z]
    const float* __restrict__ mean_zz,   // [z, z]
    const float* __restrict__ mean_w_in, // [l, z, p]
    const float* __restrict__ alpha_in,  // [l, z, p]
    const float* __restrict__ tau_p,     // scalar
    const float* __restrict__ tau0,      // [l, z]
    float* __restrict__ ztx_stash,       // [z][PSTRIDE]  (= out_mw base)
    float* __restrict__ W_stash,         // [z][PSTRIDE]  (= out_alpha base)
    float* __restrict__ out_vw)          // [l, z]
{
  const int gid = blockIdx.x * NTA + threadIdx.x;
  const bool active = (gid < P_DIM);

  if (gid < L_DIM * Z_DIM) {
    int k = gid % Z_DIM;
    out_vw[gid] = 1.0f / (tau_p[0] * mean_zz[k * Z_DIM + k] + tau0[gid]);
  }

  // ztx[k] = sum_n mean_z[n,k] * data[n,gid]
  float ztx[Z_DIM];
#pragma unroll
  for (int k = 0; k < Z_DIM; k++) ztx[k] = 0.f;
  {
    const float* dcol = data + gid;
#pragma unroll 8
    for (int n = 0; n < N_DIM; n++) {
      float d = active ? dcol[(size_t)n * P_DIM] : 0.f;
#pragma unroll
      for (int k = 0; k < Z_DIM; k++) ztx[k] += mean_z[n * Z_DIM + k] * d;
    }
  }
#pragma unroll
  for (int k = 0; k < Z_DIM; k++) ztx_stash[(size_t)k * PSTRIDE + gid] = ztx[k];

  // W[j] = sum_l mean_w[l,j,gid] * alpha[l,j,gid]
  float W[Z_DIM];
#pragma unroll
  for (int j = 0; j < Z_DIM; j++) W[j] = 0.f;
  for (int l = 0; l < L_DIM; l++) {
#pragma unroll
    for (int j = 0; j < Z_DIM; j++) {
      if (active) {
        size_t idx = ((size_t)(l * Z_DIM + j)) * P_DIM + gid;
        W[j] += mean_w_in[idx] * alpha_in[idx];
      }
    }
  }
#pragma unroll
  for (int j = 0; j < Z_DIM; j++) W_stash[(size_t)j * PSTRIDE + gid] = W[j];
}

// ---------------- Phase B: latency-bound sequential loop ----------------
__global__ __launch_bounds__(NT_B) void loading_model_seq(
    const float* __restrict__ mean_zz,   // [z, z]
    const float* __restrict__ mean_w_in, // [l, z, p]
    const float* __restrict__ alpha_in,  // [l, z, p]
    const float* __restrict__ tau_p,     // scalar
    const float* __restrict__ tau0,      // [l, z]
    const float* __restrict__ pi,        // [z, p]
    const float* __restrict__ ztx_stash, // [z][PSTRIDE]
    const float* __restrict__ W_stash,   // [z][PSTRIDE]
    float* __restrict__ out_mw,          // [l, z, p]
    float* __restrict__ out_alpha,       // [l, z, p]
    u64* __restrict__ slots)             // [2][NBLK_B]
{
  const int tid  = threadIdx.x;
  const int blk  = blockIdx.x;
  const int gid  = blk * NT_B + tid;
  const bool active = (gid < P_DIM);
  const int lane = tid & 63;
  const int wid  = tid >> 6;   // 0..15
  const float tau = tau_p[0];

  __shared__ float lds_wmax[NWAVE_B];
  __shared__ float lds_wsum[NWAVE_B];
  __shared__ float lds_lse;

  // Carried state from the stash (all reads precede any global sync / any
  // overlapping store — see header comment).
  float ztx[Z_DIM], W[Z_DIM];
#pragma unroll
  for (int k = 0; k < Z_DIM; k++) ztx[k] = ztx_stash[(size_t)k * PSTRIDE + gid];
#pragma unroll
  for (int j = 0; j < Z_DIM; j++) W[j] = W_stash[(size_t)j * PSTRIDE + gid];

  float pival = active ? pi[gid] : 1.0f;
  float mw = 0.f, av = 0.f;
  if (active) { mw = mean_w_in[gid]; av = alpha_in[gid]; } // (l=0,k=0)

  // Step-constant prefetch (two __logf's off the critical path).
  const float E0    = mean_zz[0];
  const float ktau0 = tau * E0;
  float cs2   = 1.0f / ktau0;
  float czsc2 = tau / E0;
  float nc0, nc1, nmnc;
  {
    const float t0    = tau0[0];
    const float s0inv = 1.0f / t0;
    const float s2p   = cs2 + s0inv;
    nc0  = 0.5f * (__logf(cs2) - __logf(s2p));
    nc1  = 0.5f * czsc2 * (s0inv / s2p);
    nmnc = tau / (ktau0 + t0);
  }

#pragma unroll
  for (int k = 0; k < Z_DIM; k++) {
    const float E    = mean_zz[k * Z_DIM + k];
    const float ktau = tau * E;

    float acc = 0.f;
#pragma unroll
    for (int j = 0; j < Z_DIM; j++) acc += mean_zz[k * Z_DIM + j] * W[j];
    const float RtZk = ztx[k] - (acc - E * W[k]);
    const float lpk  = active ? __logf(pival) : -INFINITY;
    if (k + 1 < Z_DIM && active) pival = pi[(size_t)(k + 1) * P_DIM + gid];

    float Wk = W[k];
    for (int l = 0; l < L_DIM; l++) {
      const float c0  = nc0;
      const float c1  = nc1;
      const float mnc = nmnc;

      const float Wkl = Wk - mw * av;
      const float E_R = RtZk - E * Wkl;
      const float mean_new = mnc * E_R;
      float logit = lpk + c0 + c1 * E_R * E_R;
      if (!active) logit = -INFINITY;

      const size_t oidx = ((size_t)(l * Z_DIM + k)) * P_DIM + gid;
      if (active) out_mw[oidx] = mean_new;   // store early: overlap with wait

      // ---- per-wave softmax stats ----
      float wmax = wred_max(logit);
      float ew   = active ? __expf(logit - wmax) : 0.f;
      float wsum = wred_sum(ew);
      if (lane == 0) { lds_wmax[wid] = wmax; lds_wsum[wid] = wsum; }
      __syncthreads();

      const int s   = k * L_DIM + l + 1;   // step tag, 1..200
      const int buf = s & 1;
      if (wid == 0) {
        // parallel 16-wave merge in wave 0 (replaces serial tid0 combine)
        const int li = lane & (NWAVE_B - 1);
        const bool val = (lane < NWAVE_B);
        float m  = lds_wmax[li];
        float sv = lds_wsum[li];
        m  = val ? m  : -INFINITY;
        sv = val ? sv : 0.f;
        float M = wred_max(m);
        float S = wred_sum(val ? __expf(m - M) * sv : 0.f);
        if (lane == 0) {
          float lse_b = M + __logf(S);
          __hip_atomic_store(&slots[buf * NBLK_B + blk],
                             (((u64)(unsigned)s) << 32) | (u64)__float_as_uint(lse_b),
                             __ATOMIC_RELAXED, __HIP_MEMORY_SCOPE_AGENT);
        }
      }

      // ---- overlap with the wait: next step's mean_w/alpha + constants ----
      float mw_n = 0.f, av_n = 0.f;
      {
        int ln = l + 1, kn = k;
        if (ln == L_DIM) { ln = 0; kn = k + 1; }
        if (kn < Z_DIM) {
          if (active) {
            size_t idx2 = ((size_t)(ln * Z_DIM + kn)) * P_DIM + gid;
            mw_n = mean_w_in[idx2];
            av_n = alpha_in[idx2];
          }
          if (ln == 0) {  // entering next k: refresh per-k constants
            const float En = mean_zz[kn * Z_DIM + kn];
            const float kt = tau * En;
            cs2   = 1.0f / kt;
            czsc2 = tau / En;
          }
          const float t0n   = tau0[ln * Z_DIM + kn];
          const float s0inv = 1.0f / t0n;
          const float s2p   = cs2 + s0inv;
          nc0  = 0.5f * (__logf(cs2) - __logf(s2p));
          nc1  = 0.5f * czsc2 * (s0inv / s2p);
          nmnc = (ln == 0) ? tau / (tau * mean_zz[kn * Z_DIM + kn] + t0n)
                           : tau / (ktau + t0n);
        }
      }

      // ---- flat one-hop combine: wave 0 polls 49 slots (1 load/lane) ----
      if (wid == 0) {
        bool need = (lane < NBLK_B);
        u64 raw = 0;
        while (need) {
          raw = __hip_atomic_load(&slots[buf * NBLK_B + lane],
                                  __ATOMIC_RELAXED, __HIP_MEMORY_SCOPE_AGENT);
          if ((unsigned)(raw >> 32) == (unsigned)s) need = false;
        }
        float bl = (lane < NBLK_B) ? __uint_as_float((unsigned)raw) : -INFINITY;
        float M  = wred_max(bl);
        float ps = (lane < NBLK_B) ? __expf(bl - M) : 0.f;
        float S  = wred_sum(ps);
        if (lane == 0) lds_lse = M + __logf(S);
      }
      __syncthreads();

      const float LSEt = lds_lse;
      const float alpha_new = active ? __expf(logit - LSEt) : 0.f;
      Wk = Wkl + mean_new * alpha_new;
      if (active) out_alpha[oidx] = alpha_new;
      mw = mw_n;
      av = av_n;
    }
    W[k] = Wk;  // commit for subsequent factors' RtZk
  }
}

extern "C" void kernel_launch(void* const* d_in, const int* in_sizes, int n_in,
                              void* d_out, int out_size, void* d_ws, size_t ws_size,
                              hipStream_t stream) {
  const float* data    = (const float*)d_in[0];
  const float* mean_z  = (const float*)d_in[1];
  const float* mean_zz = (const float*)d_in[2];
  const float* mean_w  = (const float*)d_in[3];
  // d_in[4] = var_w (unused: fully overwritten)
  const float* alpha   = (const float*)d_in[5];
  const float* tau     = (const float*)d_in[6];
  const float* tau0    = (const float*)d_in[7];
  const float* pi      = (const float*)d_in[8];

  float* out_mw    = (float*)d_out;
  float* out_vw    = out_mw + (size_t)L_DIM * Z_DIM * P_DIM;
  float* out_alpha = out_vw + (size_t)L_DIM * Z_DIM;
  u64*   ws        = (u64*)d_ws;

  // Stash lives in the out buffers (each slice is 20*50176*4B ~= 4 MB,
  // fully overwritten by phase B afterwards). Avoids assuming ws capacity.
  float* ztx_stash = out_mw;
  float* W_stash   = out_alpha;

  // Clear tags (poison is also tag-safe; memset keeps graph replays clean).
  hipMemsetAsync(d_ws, 0, 2 * NBLK_B * sizeof(u64), stream);

  hipLaunchKernelGGL(precompute_kernel, dim3(NBLKA), dim3(NTA), 0, stream,
                     data, mean_z, mean_zz, mean_w, alpha, tau, tau0,
                     ztx_stash, W_stash, out_vw);

  void* args[] = {(void*)&mean_zz, (void*)&mean_w, (void*)&alpha,
                  (void*)&tau, (void*)&tau0, (void*)&pi,
                  (void*)&ztx_stash, (void*)&W_stash,
                  (void*)&out_mw, (void*)&out_alpha, (void*)&ws};
  hipLaunchCooperativeKernel((void*)loading_model_seq, dim3(NBLK_B),
                             dim3(NT_B), args, 0, stream);
}

// Round 2
// 1161.013 us; speedup vs baseline: 1.1914x; 1.1914x over previous
//
#include <hip/hip_runtime.h>
#include <stdint.h>

// Two-phase LoadingModel CAVI update: n=1000, p=50000, z=20, l=10.
//
// Phase A (3582x128, plain launch): bandwidth phase with REAL occupancy.
//   ztx split into NSZ=4 n-slices (250 rows each), W split into NSW=5
//   l-slices (2 l each) -> ~7k waves (12/CU) so HBM latency is hidden
//   (prev round: 1 wave/SIMD, ~430 us for a 280 MB job).
//   Partials stash into the OUT buffers:
//     ztx partials -> out_mw  [s][k][PSTRIDE], s=0..3   (16.3 MB of 40)
//     W   partials -> out_alpha[s][j][PSTRIDE], s=0..4   (20.4 MB of 40)
//   Phase B sums partials in its prologue. Hazard: B's only write into the
//   stash region before the first global combine is step (0,0)'s
//   out_mw[col] -- a same-thread read-then-write. All other overlapping
//   writes happen after the tag-1 combine, i.e. after all prologues.
//
// Phase B (cooperative 53x1024): latency phase -- 200 sequential global
//   softmaxes. NEW: wave 0 of each block is a dedicated COMM wave (owns no
//   columns): it only merges the 15 work-wave partials, publishes the block
//   lse, and polls the 53 slots (1 load/lane). Work waves' next-step
//   prefetch fully overlaps the wait and never delays the poll loop.

#define NTA 128
#define NBA 398             // blocks per slice in phase A: 398*128 = 50944
#define NSZ 4               // n-slices for ztx (250 rows each)
#define NSW 5               // l-slices for W (2 l each)
#define PSTRIDE 50944       // padded column stride for stashes

#define NT_B 1024
#define NWAVE_B 16
#define COLS_B 960          // 15 work waves * 64
#define NBLK_B 53           // 53*960 = 50880 >= 50000

constexpr int N_DIM = 1000;
constexpr int P_DIM = 50000;
constexpr int Z_DIM = 20;
constexpr int L_DIM = 10;

static_assert(NTA * NBA == PSTRIDE, "A covers PSTRIDE columns");
static_assert(NBLK_B * COLS_B >= P_DIM, "B covers all real columns");
static_assert(NBLK_B * COLS_B <= PSTRIDE, "B stash reads in bounds");
static_assert(NBLK_B <= 64, "one poll load per lane");

using u64 = unsigned long long;

__device__ __forceinline__ float wred_max(float v) {
#pragma unroll
  for (int m = 32; m; m >>= 1) v = fmaxf(v, __shfl_xor(v, m, 64));
  return v;
}
__device__ __forceinline__ float wred_sum(float v) {
#pragma unroll
  for (int m = 32; m; m >>= 1) v += __shfl_xor(v, m, 64);
  return v;
}

// ---------------- Phase A: bandwidth-bound precompute ----------------
__global__ __launch_bounds__(NTA) void precompute_kernel(
    const float* __restrict__ data,      // [n, p]
    const float* __restrict__ mean_z,    // [n, z]
    const float* __restrict__ mean_zz,   // [z, z]
    const float* __restrict__ mean_w_in, // [l, z, p]
    const float* __restrict__ alpha_in,  // [l, z, p]
    const float* __restrict__ tau_p,     // scalar
    const float* __restrict__ tau0,      // [l, z]
    float* __restrict__ ztx_stash,       // [NSZ][z][PSTRIDE] (= out_mw)
    float* __restrict__ W_stash,         // [NSW][z][PSTRIDE] (= out_alpha)
    float* __restrict__ out_vw)          // [l, z]
{
  const int bid  = blockIdx.x;
  const int role = bid / NBA;            // 0..NSZ-1: ztx; NSZ..NSZ+NSW-1: W
  const int b2   = bid % NBA;
  const int col  = b2 * NTA + threadIdx.x;   // < PSTRIDE by construction
  const bool act = (col < P_DIM);

  if (role == 0 && b2 < 2) {
    int g = b2 * NTA + threadIdx.x;
    if (g < L_DIM * Z_DIM) {
      int k = g % Z_DIM;
      out_vw[g] = 1.0f / (tau_p[0] * mean_zz[k * Z_DIM + k] + tau0[g]);
    }
  }

  if (role < NSZ) {
    // ztx partial over rows [s*250, s*250+250)
    const int s  = role;
    const int n0 = s * (N_DIM / NSZ);
    const int n1 = n0 + (N_DIM / NSZ);
    float z[Z_DIM];
#pragma unroll
    for (int k = 0; k < Z_DIM; k++) z[k] = 0.f;
    const float* dcol = data + col;
#pragma unroll 8
    for (int n = n0; n < n1; n++) {
      float d = act ? dcol[(size_t)n * P_DIM] : 0.f;
#pragma unroll
      for (int k = 0; k < Z_DIM; k++) z[k] += mean_z[n * Z_DIM + k] * d;
    }
#pragma unroll
    for (int k = 0; k < Z_DIM; k++)
      ztx_stash[(size_t)(s * Z_DIM + k) * PSTRIDE + col] = z[k];
  } else {
    // W partial over l in {2s, 2s+1}
    const int s = role - NSZ;
    float Wp[Z_DIM];
#pragma unroll
    for (int j = 0; j < Z_DIM; j++) Wp[j] = 0.f;
#pragma unroll
    for (int li = 0; li < 2; li++) {
      const int l = 2 * s + li;
#pragma unroll
      for (int j = 0; j < Z_DIM; j++) {
        if (act) {
          size_t idx = ((size_t)(l * Z_DIM + j)) * P_DIM + col;
          Wp[j] += mean_w_in[idx] * alpha_in[idx];
        }
      }
    }
#pragma unroll
    for (int j = 0; j < Z_DIM; j++)
      W_stash[(size_t)(s * Z_DIM + j) * PSTRIDE + col] = Wp[j];
  }
}

// ---------------- Phase B: latency-bound sequential loop ----------------
__global__ __launch_bounds__(NT_B) void loading_model_seq(
    const float* __restrict__ mean_zz,   // [z, z]
    const float* __restrict__ mean_w_in, // [l, z, p]
    const float* __restrict__ alpha_in,  // [l, z, p]
    const float* __restrict__ tau_p,     // scalar
    const float* __restrict__ tau0,      // [l, z]
    const float* __restrict__ pi,        // [z, p]
    const float* __restrict__ ztx_stash, // [NSZ][z][PSTRIDE]
    const float* __restrict__ W_stash,   // [NSW][z][PSTRIDE]
    float* __restrict__ out_mw,          // [l, z, p]
    float* __restrict__ out_alpha,       // [l, z, p]
    u64* __restrict__ slots)             // [2][NBLK_B]
{
  const int tid  = threadIdx.x;
  const int blk  = blockIdx.x;
  const int lane = tid & 63;
  const int wid  = tid >> 6;             // 0 = comm wave, 1..15 = work
  const bool work = (wid > 0);
  const int col  = blk * COLS_B + (tid - 64);  // valid iff work
  const bool active = work && (col < P_DIM);
  const float tau = tau_p[0];

  __shared__ float lds_wmax[NWAVE_B];
  __shared__ float lds_wsum[NWAVE_B];
  __shared__ float lds_lse;

  // ---- prologue: sum stash partials (reads strictly precede any
  //      cross-thread write into the stash regions; see header) ----
  float ztx[Z_DIM], W[Z_DIM];
#pragma unroll
  for (int k = 0; k < Z_DIM; k++) ztx[k] = 0.f;
#pragma unroll
  for (int j = 0; j < Z_DIM; j++) W[j] = 0.f;
  if (work) {
#pragma unroll
    for (int s = 0; s < NSZ; s++)
#pragma unroll
      for (int k = 0; k < Z_DIM; k++)
        ztx[k] += ztx_stash[(size_t)(s * Z_DIM + k) * PSTRIDE + col];
#pragma unroll
    for (int s = 0; s < NSW; s++)
#pragma unroll
      for (int j = 0; j < Z_DIM; j++)
        W[j] += W_stash[(size_t)(s * Z_DIM + j) * PSTRIDE + col];
  }

  float pival = active ? pi[col] : 1.0f;
  float mw = 0.f, av = 0.f;
  if (active) { mw = mean_w_in[col]; av = alpha_in[col]; } // (l=0,k=0)

  // Step-constant prefetch (kept off the critical path thereafter).
  const float E0    = mean_zz[0];
  const float ktau0 = tau * E0;
  float cs2   = 1.0f / ktau0;
  float czsc2 = tau / E0;
  float nc0, nc1, nmnc;
  {
    const float t0    = tau0[0];
    const float s0inv = 1.0f / t0;
    const float s2p   = cs2 + s0inv;
    nc0  = 0.5f * (__logf(cs2) - __logf(s2p));
    nc1  = 0.5f * czsc2 * (s0inv / s2p);
    nmnc = tau / (ktau0 + t0);
  }

#pragma unroll
  for (int k = 0; k < Z_DIM; k++) {
    const float E    = mean_zz[k * Z_DIM + k];
    const float ktau = tau * E;

    float acc = 0.f;
#pragma unroll
    for (int j = 0; j < Z_DIM; j++) acc += mean_zz[k * Z_DIM + j] * W[j];
    const float RtZk = ztx[k] - (acc - E * W[k]);
    const float lpk  = active ? __logf(pival) : -INFINITY;
    if (k + 1 < Z_DIM && active) pival = pi[(size_t)(k + 1) * P_DIM + col];

    float Wk = W[k];
    for (int l = 0; l < L_DIM; l++) {
      const float c0  = nc0;
      const float c1  = nc1;
      const float mnc = nmnc;

      const float Wkl = Wk - mw * av;
      const float E_R = RtZk - E * Wkl;
      const float mean_new = mnc * E_R;
      float logit = lpk + c0 + c1 * E_R * E_R;
      if (!active) logit = -INFINITY;

      const size_t oidx = ((size_t)(l * Z_DIM + k)) * P_DIM + col;
      if (active) out_mw[oidx] = mean_new;   // store early: overlap with wait

      // ---- per-wave softmax stats (work waves only publish to LDS) ----
      float wmax = wred_max(logit);
      float ew   = active ? __expf(logit - wmax) : 0.f;
      float wsum = wred_sum(ew);
      if (work && lane == 0) { lds_wmax[wid] = wmax; lds_wsum[wid] = wsum; }
      __syncthreads();

      const int s   = k * L_DIM + l + 1;   // step tag, 1..200
      const int buf = s & 1;

      if (wid == 0) {
        // comm wave: merge 15 work-wave partials, publish, poll, combine.
        const bool val = (lane >= 1 && lane < NWAVE_B);
        float m  = val ? lds_wmax[lane] : -INFINITY;
        float sv = val ? lds_wsum[lane] : 0.f;
        float M  = wred_max(m);
        float S  = wred_sum(val ? __expf(m - M) * sv : 0.f);
        if (lane == 0) {
          float lse_b = M + __logf(S);
          __hip_atomic_store(&slots[buf * NBLK_B + blk],
                             (((u64)(unsigned)s) << 32) | (u64)__float_as_uint(lse_b),
                             __ATOMIC_RELAXED, __HIP_MEMORY_SCOPE_AGENT);
        }
        bool need = (lane < NBLK_B);
        u64 raw = 0;
        while (need) {
          raw = __hip_atomic_load(&slots[buf * NBLK_B + lane],
                                  __ATOMIC_RELAXED, __HIP_MEMORY_SCOPE_AGENT);
          if ((unsigned)(raw >> 32) == (unsigned)s) need = false;
        }
        float bl = (lane < NBLK_B) ? __uint_as_float((unsigned)raw) : -INFINITY;
        float Mg = wred_max(bl);
        float ps = (lane < NBLK_B) ? __expf(bl - Mg) : 0.f;
        float Sg = wred_sum(ps);
        if (lane == 0) lds_lse = Mg + __logf(Sg);
      } else {
        // work waves: next step's mean_w/alpha + constants overlap the wait
        float mw_n = 0.f, av_n = 0.f;
        int ln = l + 1, kn = k;
        if (ln == L_DIM) { ln = 0; kn = k + 1; }
        if (kn < Z_DIM) {
          if (active) {
            size_t idx2 = ((size_t)(ln * Z_DIM + kn)) * P_DIM + col;
            mw_n = mean_w_in[idx2];
            av_n = alpha_in[idx2];
          }
          if (ln == 0) {  // entering next k: refresh per-k constants
            const float En = mean_zz[kn * Z_DIM + kn];
            const float kt = tau * En;
            cs2   = 1.0f / kt;
            czsc2 = tau / En;
          }
          const float t0n   = tau0[ln * Z_DIM + kn];
          const float s0inv = 1.0f / t0n;
          const float s2p   = cs2 + s0inv;
          nc0  = 0.5f * (__logf(cs2) - __logf(s2p));
          nc1  = 0.5f * czsc2 * (s0inv / s2p);
          nmnc = (ln == 0) ? tau / (tau * mean_zz[kn * Z_DIM + kn] + t0n)
                           : tau / (ktau + t0n);
        }
        mw = mw_n;
        av = av_n;
      }
      __syncthreads();

      const float LSEt = lds_lse;
      const float alpha_new = active ? __expf(logit - LSEt) : 0.f;
      Wk = Wkl + mean_new * alpha_new;
      if (active) out_alpha[oidx] = alpha_new;
    }
    W[k] = Wk;  // commit for subsequent factors' RtZk
  }
}

extern "C" void kernel_launch(void* const* d_in, const int* in_sizes, int n_in,
                              void* d_out, int out_size, void* d_ws, size_t ws_size,
                              hipStream_t stream) {
  const float* data    = (const float*)d_in[0];
  const float* mean_z  = (const float*)d_in[1];
  const float* mean_zz = (const float*)d_in[2];
  const float* mean_w  = (const float*)d_in[3];
  // d_in[4] = var_w (unused: fully overwritten)
  const float* alpha   = (const float*)d_in[5];
  const float* tau     = (const float*)d_in[6];
  const float* tau0    = (const float*)d_in[7];
  const float* pi      = (const float*)d_in[8];

  float* out_mw    = (float*)d_out;
  float* out_vw    = out_mw + (size_t)L_DIM * Z_DIM * P_DIM;
  float* out_alpha = out_vw + (size_t)L_DIM * Z_DIM;
  u64*   ws        = (u64*)d_ws;

  // Stashes live in the out buffers (NSZ*20*PSTRIDE*4 = 16.3 MB and
  // NSW*20*PSTRIDE*4 = 20.4 MB, both < 40 MB; fully overwritten later).
  float* ztx_stash = out_mw;
  float* W_stash   = out_alpha;

  hipMemsetAsync(d_ws, 0, 2 * NBLK_B * sizeof(u64), stream);

  hipLaunchKernelGGL(precompute_kernel, dim3((NSZ + NSW) * NBA), dim3(NTA),
                     0, stream,
                     data, mean_z, mean_zz, mean_w, alpha, tau, tau0,
                     ztx_stash, W_stash, out_vw);

  void* args[] = {(void*)&mean_zz, (void*)&mean_w, (void*)&alpha,
                  (void*)&tau, (void*)&tau0, (void*)&pi,
                  (void*)&ztx_stash, (void*)&W_stash,
                  (void*)&out_mw, (void*)&out_alpha, (void*)&ws};
  hipLaunchCooperativeKernel((void*)loading_model_seq, dim3(NBLK_B),
                             dim3(NT_B), args, 0, stream);
}